// Round 5
// baseline (8130.702 us; speedup 1.0000x reference)
//
#include <hip/hip_runtime.h>

#define BB 4
#define NN 32768
#define BN 131072
#define WD 256
#define NDEPTH 8
#define MS 32
#define NH 8
#define DHD 32
#define FF 1024

typedef float f32x4 __attribute__((ext_vector_type(4)));
typedef float f32x2 __attribute__((ext_vector_type(2)));
typedef _Float16 f16x8 __attribute__((ext_vector_type(8)));
typedef _Float16 f16x4 __attribute__((ext_vector_type(4)));

__device__ __forceinline__ float rcp_(float x){ return __builtin_amdgcn_rcpf(x); }
__device__ __forceinline__ float rsq_(float x){ return __builtin_amdgcn_rsqf(x); }

// gelu (exact erf variant) via Abramowitz-Stegun 7.1.26, |err| <= 1.5e-7
__device__ __forceinline__ float gelu_f(float x){
  float z  = 0.70710678118654752f * x;
  float az = fabsf(z);
  float t  = rcp_(fmaf(0.3275911f, az, 1.0f));
  float p  = fmaf(t, 1.061405429f, -1.453152027f);
  p = fmaf(t, p, 1.421413741f);
  p = fmaf(t, p, -0.284496736f);
  p = fmaf(t, p, 0.254829592f);
  p = p * t;
  float e  = __expf(-az*az);
  float er = 1.0f - p*e;
  er = (z < 0.0f) ? -er : er;
  return 0.5f * x * (1.0f + er);
}

// ---------- prep: weight transpose/convert (once per call) ----------
__global__ __launch_bounds__(256) void k_prep_w1t(const float* __restrict__ f1w,
                                                  const float* __restrict__ ln2g,
                                                  _Float16* __restrict__ W1T){
  int id = blockIdx.x*256 + threadIdx.x;      // 8*1024*256
  int k = id & 255; int f = (id >> 8) & 1023; int i = id >> 18;
  W1T[id] = (_Float16)(ln2g[i*256+k] * f1w[(size_t)i*262144 + (size_t)k*1024 + f]);
}
__global__ __launch_bounds__(256) void k_prep_w2t(const float* __restrict__ f2w,
                                                  _Float16* __restrict__ W2T){
  int id = blockIdx.x*256 + threadIdx.x;      // 8*256*1024
  int k = id & 1023; int n = (id >> 10) & 255; int i = id >> 18;
  W2T[id] = (_Float16)(f2w[(size_t)i*262144 + (size_t)k*256 + n]);
}
__global__ __launch_bounds__(256) void k_prep_s1c1(const float* __restrict__ f1w,
                                                   const float* __restrict__ ln2g,
                                                   const float* __restrict__ ln2b,
                                                   const float* __restrict__ f1b,
                                                   float* __restrict__ S1, float* __restrict__ C1){
  int fb = blockIdx.x; int i = blockIdx.y; int t = threadIdx.x;
  int f = fb*256 + t;
  const float* w = f1w + (size_t)i*262144 + f;
  float s = 0.f, c = 0.f;
  for (int k = 0; k < 256; ++k){
    float wv = w[(size_t)k*1024];
    s = fmaf(ln2g[i*256+k], wv, s);
    c = fmaf(ln2b[i*256+k], wv, c);
  }
  S1[i*1024+f] = s;
  C1[i*1024+f] = c + f1b[i*1024+f];
}

// ---------- encode: x = concat(features, LFF(coords), TE(t)) @ in_w + in_b ----------
__global__ __launch_bounds__(256) void k_encode(const float* __restrict__ feat,
                                                const float* __restrict__ coords,
                                                const float* __restrict__ tn,
                                                const float* __restrict__ fm,
                                                const float* __restrict__ om,
                                                const float* __restrict__ in_w,
                                                const float* __restrict__ in_b,
                                                float* __restrict__ X){
  __shared__ float inw[28*256];
  __shared__ float enc[8][28];
  int t = threadIdx.x;
  for (int i = 0; i < 28; ++i) inw[i*256+t] = in_w[i*256+t];
  float bv = in_b[t];
  int row0 = blockIdx.x * 128;
  __syncthreads();
  for (int it = 0; it < 16; ++it){
    int rbase = row0 + it*8;
    if (t < 224){
      int rr = t / 28, j = t - rr*28;
      int row = rbase + rr; int b = row >> 15;
      float v;
      if (j < 4){
        v = feat[(size_t)row*4 + j];
      } else if (j < 20){
        int fi = (j - 4) & 7;
        const float* cp = coords + (size_t)row*3;
        float pr = 6.2831853071795864f * (cp[0]*fm[fi] + cp[1]*fm[8+fi] + cp[2]*fm[16+fi]);
        v = (j < 12) ? sinf(pr) : cosf(pr);
      } else {
        int fi = (j - 20) & 3;
        float ang = om[fi] * (tn[b] * 1000.0f);
        v = (j < 24) ? sinf(ang) : cosf(ang);
      }
      enc[rr][j] = v;
    }
    __syncthreads();
    for (int rr = 0; rr < 8; ++rr){
      float a = bv;
      #pragma unroll 7
      for (int j = 0; j < 28; ++j) a = fmaf(enc[rr][j], inw[j*256+t], a);
      X[(size_t)(rbase+rr)*256 + t] = a;
    }
    __syncthreads();
  }
}

// ---------- K1: LN1 + slice logits + softmax -> w ; accumulate S (numerator) & wsum ----------
__global__ __launch_bounds__(256) void k_slice(const float* __restrict__ X,
                                               float* __restrict__ Wb,
                                               float* __restrict__ S,
                                               float* __restrict__ WS,
                                               const float* __restrict__ swp,
                                               const float* __restrict__ sbp,
                                               const float* __restrict__ g1p,
                                               const float* __restrict__ b1p){
  __shared__ float hl[256];
  __shared__ float part[256];
  __shared__ float wl[32];
  __shared__ float red[8];
  int t = threadIdx.x;
  int base = (t >> 5) << 5;
  int m = t & 31;
  float swreg[32];
  #pragma unroll
  for (int j = 0; j < 32; ++j) swreg[j] = swp[(size_t)(base+j)*32 + m];
  float g1 = g1p[t], b1 = b1p[t];
  float sbv = (t < 32) ? sbp[t] : 0.f;
  float acc[32];
  #pragma unroll
  for (int i = 0; i < 32; ++i) acc[i] = 0.f;
  float wacc = 0.f;
  int row0 = blockIdx.x * 128;
  int b = row0 >> 15;
  for (int it = 0; it < 128; ++it){
    int row = row0 + it;
    float xv = X[(size_t)row*256 + t];
    float s = xv, q = xv*xv;
    #pragma unroll
    for (int off = 32; off; off >>= 1){ s += __shfl_xor(s, off); q += __shfl_xor(q, off); }
    if ((t & 63) == 0){ red[(t>>6)*2] = s; red[(t>>6)*2+1] = q; }
    __syncthreads();                                    // A
    float sum = red[0]+red[2]+red[4]+red[6];
    float sq  = red[1]+red[3]+red[5]+red[7];
    float mu  = sum * (1.f/256.f);
    float var = sq * (1.f/256.f) - mu*mu;
    float rstd = rsq_(var + 1e-5f);
    float h = (xv - mu)*rstd*g1 + b1;
    hl[t] = h;
    __syncthreads();                                    // B
    {
      float p = 0.f;
      #pragma unroll
      for (int j = 0; j < 32; ++j) p = fmaf(hl[base+j], swreg[j], p);
      part[t] = p;
    }
    __syncthreads();                                    // C
    if (t < 32){
      float lg = sbv;
      #pragma unroll
      for (int g = 0; g < 8; ++g) lg += part[g*32 + t];
      float mx = lg;
      #pragma unroll
      for (int off = 16; off; off >>= 1) mx = fmaxf(mx, __shfl_xor(mx, off));
      float e = __expf(lg - mx);
      float se = e;
      #pragma unroll
      for (int off = 16; off; off >>= 1) se += __shfl_xor(se, off);
      float wv = e * rcp_(se);
      wl[t] = wv;
      Wb[(size_t)row*32 + t] = wv;
      wacc += wv;
    }
    __syncthreads();                                    // D
    #pragma unroll
    for (int i = 0; i < 32; ++i) acc[i] = fmaf(wl[i], h, acc[i]);
  }
  #pragma unroll 8
  for (int i = 0; i < 32; ++i) atomicAdd(&S[(size_t)(b*32+i)*256 + t], acc[i]);
  if (t < 32) atomicAdd(&WS[b*32 + t], wacc);
}

// ---------- K2: tiny MHA on (B, 32, 256); one block per (batch, head) ----------
__global__ __launch_bounds__(256) void k_mha(const float* __restrict__ S,
                                             const float* __restrict__ WS,
                                             float* __restrict__ O,
                                             const float* __restrict__ qkvw,
                                             const float* __restrict__ qkvb){
  __shared__ float zl[32*256];
  __shared__ float qkl[3][32][33];
  __shared__ float att[32][33];
  __shared__ float wsl[32];
  int t = threadIdx.x;
  int b = blockIdx.x >> 3, h = blockIdx.x & 7;
  if (t < 32) wsl[t] = rcp_(fmaxf(WS[b*32+t], 1e-8f));
  __syncthreads();
  for (int i = 0; i < 32; ++i){
    int e = i*256 + t; int mm = e >> 8; int d = e & 255;
    zl[e] = S[(size_t)(b*32+mm)*256 + d] * wsl[mm];
  }
  __syncthreads();
  for (int i = 0; i < 12; ++i){
    int o = i*256 + t;
    int which = o >> 10, rem = o & 1023, mm = rem >> 5, dh = rem & 31;
    int col = which*256 + h*32 + dh;
    float a = qkvb[col];
    const float* zp = &zl[mm*256];
    const float* wp = qkvw + col;
    #pragma unroll 4
    for (int d = 0; d < 256; ++d) a = fmaf(zp[d], wp[(size_t)d*768], a);
    qkl[which][mm][dh] = a;
  }
  __syncthreads();
  for (int i = 0; i < 4; ++i){
    int e = i*256 + t; int mm = e >> 5; int k2 = e & 31;
    float a = 0.f;
    #pragma unroll 8
    for (int d = 0; d < 32; ++d) a = fmaf(qkl[0][mm][d], qkl[1][k2][d], a);
    att[mm][k2] = a * 0.17677669529663687f;
  }
  __syncthreads();
  {
    int mm = t >> 3, j = t & 7;
    float v0 = att[mm][j], v1 = att[mm][j+8], v2 = att[mm][j+16], v3 = att[mm][j+24];
    float mx = fmaxf(fmaxf(v0, v1), fmaxf(v2, v3));
    #pragma unroll
    for (int off = 4; off; off >>= 1) mx = fmaxf(mx, __shfl_xor(mx, off));
    v0 = __expf(v0-mx); v1 = __expf(v1-mx); v2 = __expf(v2-mx); v3 = __expf(v3-mx);
    float sm = v0+v1+v2+v3;
    #pragma unroll
    for (int off = 4; off; off >>= 1) sm += __shfl_xor(sm, off);
    float inv = rcp_(sm);
    att[mm][j] = v0*inv; att[mm][j+8] = v1*inv; att[mm][j+16] = v2*inv; att[mm][j+24] = v3*inv;
  }
  __syncthreads();
  for (int i = 0; i < 4; ++i){
    int e = i*256 + t; int mm = e >> 5; int dh = e & 31;
    float a = 0.f;
    #pragma unroll 8
    for (int k2 = 0; k2 < 32; ++k2) a = fmaf(att[mm][k2], qkl[2][k2][dh], a);
    O[(size_t)(b*32+mm)*256 + h*32 + dh] = a;
  }
}

// ---------- K3: slices_out = o @ attn_out_w + attn_out_b ----------
__global__ __launch_bounds__(256) void k_outproj(const float* __restrict__ O,
                                                 float* __restrict__ SO,
                                                 const float* __restrict__ aow,
                                                 const float* __restrict__ aob){
  __shared__ float orow[256];
  int t = threadIdx.x; int row = blockIdx.x;
  orow[t] = O[(size_t)row*256 + t];
  __syncthreads();
  float a = aob[t];
  #pragma unroll 4
  for (int d = 0; d < 256; ++d) a = fmaf(orow[d], aow[(size_t)d*256 + t], a);
  SO[(size_t)row*256 + t] = a;
}

// ---------- K4: x += w @ slices_out ; write LN2 stats (rstd, rstd*mu) ----------
__global__ __launch_bounds__(256) void k_deslice(float* __restrict__ X,
                                                 const float* __restrict__ Wb,
                                                 const float* __restrict__ SO,
                                                 float* __restrict__ ST){
  __shared__ float wrow[32];
  __shared__ float red[8];
  int t = threadIdx.x;
  int row0 = blockIdx.x * 32;
  int b = row0 >> 15;
  float soc[32];
  #pragma unroll 8
  for (int i = 0; i < 32; ++i) soc[i] = SO[(size_t)(b*32+i)*256 + t];
  for (int it = 0; it < 32; ++it){
    int row = row0 + it;
    if (t < 32) wrow[t] = Wb[(size_t)row*32 + t];
    __syncthreads();
    float xv = X[(size_t)row*256 + t];
    float dv = 0.f;
    #pragma unroll
    for (int i = 0; i < 32; ++i) dv = fmaf(wrow[i], soc[i], dv);
    float xn = xv + dv;
    X[(size_t)row*256 + t] = xn;
    float s = xn, q = xn*xn;
    #pragma unroll
    for (int off = 32; off; off >>= 1){ s += __shfl_xor(s, off); q += __shfl_xor(q, off); }
    if ((t & 63) == 0){ red[(t>>6)*2] = s; red[(t>>6)*2+1] = q; }
    __syncthreads();
    if (t == 0){
      float sum = red[0]+red[2]+red[4]+red[6];
      float sq  = red[1]+red[3]+red[5]+red[7];
      float mu  = sum * (1.f/256.f);
      float var = sq * (1.f/256.f) - mu*mu;
      float rstd = rsq_(var + 1e-5f);
      ST[(size_t)row*2]   = rstd;
      ST[(size_t)row*2+1] = rstd*mu;
    }
    __syncthreads();
  }
}

// ---------- G1: u = gelu( rstd*(x@W1g) - (rstd*mu)*S1 + C1 ) , f16 out ----------
__global__ __launch_bounds__(256) void k_ffn1(const float* __restrict__ X,
                                              const _Float16* __restrict__ W1T,
                                              const float* __restrict__ S1,
                                              const float* __restrict__ C1,
                                              const float* __restrict__ ST,
                                              _Float16* __restrict__ U, int c0){
  __shared__ _Float16 As[128*40];
  __shared__ _Float16 Bs[128*40];
  __shared__ f32x2 stl[128];
  int t = threadIdx.x;
  int nb = blockIdx.x;
  int my = blockIdx.y;
  int row0 = c0 + my*128;
  int w = t >> 6, l = t & 63;
  int wm = w >> 1, wn = w & 1, lr = l & 15, lk = l >> 4;
  f32x4 acc[4][4] = {};
  for (int ks = 0; ks < 8; ++ks){
    int k0 = ks*32;
    {
      int r = t >> 3, qd = t & 7;
      #pragma unroll
      for (int i = 0; i < 4; ++i){
        int rr = i*32 + r;
        f32x4 v = *reinterpret_cast<const f32x4*>(X + (size_t)(row0+rr)*256 + k0 + qd*4);
        f16x4 hv; hv[0]=(_Float16)v[0]; hv[1]=(_Float16)v[1]; hv[2]=(_Float16)v[2]; hv[3]=(_Float16)v[3];
        *reinterpret_cast<f16x4*>(&As[rr*40 + qd*4]) = hv;
      }
      #pragma unroll
      for (int i = 0; i < 2; ++i){
        int e = i*256 + t; int fr = e >> 2; int qb = e & 3;
        f16x8 hv = *reinterpret_cast<const f16x8*>(W1T + (size_t)(nb*128+fr)*256 + k0 + qb*8);
        *reinterpret_cast<f16x8*>(&Bs[fr*40 + qb*8]) = hv;
      }
    }
    __syncthreads();
    f16x8 a[4], bf[4];
    #pragma unroll
    for (int i = 0; i < 4; ++i) a[i]  = *reinterpret_cast<const f16x8*>(&As[(64*wm + 16*i + lr)*40 + lk*8]);
    #pragma unroll
    for (int i = 0; i < 4; ++i) bf[i] = *reinterpret_cast<const f16x8*>(&Bs[(64*wn + 16*i + lr)*40 + lk*8]);
    #pragma unroll
    for (int mt = 0; mt < 4; ++mt)
      #pragma unroll
      for (int nt = 0; nt < 4; ++nt)
        acc[mt][nt] = __builtin_amdgcn_mfma_f32_16x16x32_f16(a[mt], bf[nt], acc[mt][nt], 0, 0, 0);
    __syncthreads();
  }
  if (t < 128) stl[t] = *reinterpret_cast<const f32x2*>(ST + (size_t)(row0+t)*2);
  __syncthreads();
  #pragma unroll
  for (int nt = 0; nt < 4; ++nt){
    int f = nb*128 + 64*wn + 16*nt + lr;
    float s1 = S1[f], c1 = C1[f];
    #pragma unroll
    for (int mt = 0; mt < 4; ++mt){
      int lrow0 = 64*wm + 16*mt + lk*4;
      #pragma unroll
      for (int e = 0; e < 4; ++e){
        f32x2 st2 = stl[lrow0 + e];
        float u = st2[0]*acc[mt][nt][e] - st2[1]*s1 + c1;
        U[(size_t)(my*128 + lrow0 + e)*1024 + f] = (_Float16)gelu_f(u);
      }
    }
  }
}

// ---------- G2: x += u @ W2 + b2 ----------
__global__ __launch_bounds__(256) void k_ffn2(const _Float16* __restrict__ U,
                                              const _Float16* __restrict__ W2T,
                                              const float* __restrict__ f2b,
                                              float* __restrict__ X, int c0){
  __shared__ _Float16 As[128*40];
  __shared__ _Float16 Bs[128*40];
  int t = threadIdx.x;
  int nb = blockIdx.x;
  int my = blockIdx.y;
  int w = t >> 6, l = t & 63;
  int wm = w >> 1, wn = w & 1, lr = l & 15, lk = l >> 4;
  f32x4 acc[4][4] = {};
  for (int ks = 0; ks < 32; ++ks){
    int k0 = ks*32;
    #pragma unroll
    for (int i = 0; i < 2; ++i){
      int e = i*256 + t; int r = e >> 2; int qb = e & 3;
      f16x8 hv  = *reinterpret_cast<const f16x8*>(U   + (size_t)(my*128+r)*1024 + k0 + qb*8);
      *reinterpret_cast<f16x8*>(&As[r*40 + qb*8]) = hv;
      f16x8 hv2 = *reinterpret_cast<const f16x8*>(W2T + (size_t)(nb*128+r)*1024 + k0 + qb*8);
      *reinterpret_cast<f16x8*>(&Bs[r*40 + qb*8]) = hv2;
    }
    __syncthreads();
    f16x8 a[4], bf[4];
    #pragma unroll
    for (int i = 0; i < 4; ++i) a[i]  = *reinterpret_cast<const f16x8*>(&As[(64*wm + 16*i + lr)*40 + lk*8]);
    #pragma unroll
    for (int i = 0; i < 4; ++i) bf[i] = *reinterpret_cast<const f16x8*>(&Bs[(64*wn + 16*i + lr)*40 + lk*8]);
    #pragma unroll
    for (int mt = 0; mt < 4; ++mt)
      #pragma unroll
      for (int nt = 0; nt < 4; ++nt)
        acc[mt][nt] = __builtin_amdgcn_mfma_f32_16x16x32_f16(a[mt], bf[nt], acc[mt][nt], 0, 0, 0);
    __syncthreads();
  }
  #pragma unroll
  for (int nt = 0; nt < 4; ++nt){
    int c = nb*128 + 64*wn + 16*nt + lr;
    float bv = f2b[c];
    #pragma unroll
    for (int mt = 0; mt < 4; ++mt){
      int gr = c0 + my*128 + 64*wm + 16*mt + lk*4;
      #pragma unroll
      for (int e = 0; e < 4; ++e){
        size_t idx = (size_t)(gr+e)*256 + c;
        X[idx] = X[idx] + acc[mt][nt][e] + bv;
      }
    }
  }
}

// ---------- final: out = x @ out_w + out_b ----------
__global__ __launch_bounds__(256) void k_final(const float* __restrict__ X,
                                               const float* __restrict__ out_w,
                                               const float* __restrict__ out_b,
                                               float* __restrict__ out){
  int t = threadIdx.x; int w = t >> 6; int l = t & 63;
  f32x4 ow[4];
  #pragma unroll
  for (int j = 0; j < 4; ++j) ow[j] = *reinterpret_cast<const f32x4*>(out_w + (4*l+j)*4);
  f32x4 ob = *reinterpret_cast<const f32x4*>(out_b);
  int row0 = blockIdx.x * 256;
  for (int it = 0; it < 64; ++it){
    int row = row0 + it*4 + w;
    f32x4 xv = *reinterpret_cast<const f32x4*>(X + (size_t)row*256 + 4*l);
    f32x4 p = ow[0]*xv[0];
    p += ow[1]*xv[1]; p += ow[2]*xv[2]; p += ow[3]*xv[3];
    #pragma unroll
    for (int off = 32; off; off >>= 1){
      p[0] += __shfl_xor(p[0], off);
      p[1] += __shfl_xor(p[1], off);
      p[2] += __shfl_xor(p[2], off);
      p[3] += __shfl_xor(p[3], off);
    }
    if (l == 0) *reinterpret_cast<f32x4*>(out + (size_t)row*4) = p + ob;
  }
}

// ---------- host ----------
static constexpr size_t OFF_X   = 0;
static constexpr size_t SZ_X    = (size_t)BN*256*4;            // 134217728
static constexpr size_t OFF_W   = OFF_X + SZ_X;
static constexpr size_t SZ_W    = (size_t)BN*32*4;             // 16777216
static constexpr size_t OFF_ST  = OFF_W + SZ_W;
static constexpr size_t SZ_ST   = (size_t)BN*2*4;              // 1048576
static constexpr size_t OFF_S   = OFF_ST + SZ_ST;
static constexpr size_t SZ_S    = (size_t)4*32*256*4;          // 131072
static constexpr size_t OFF_WS  = OFF_S + SZ_S;
static constexpr size_t OFF_O   = OFF_WS + 1024;
static constexpr size_t OFF_SO  = OFF_O + 131072;
static constexpr size_t OFF_W1T = OFF_SO + 131072;
static constexpr size_t SZ_W1T  = (size_t)8*1024*256*2;        // 4194304
static constexpr size_t OFF_W2T = OFF_W1T + SZ_W1T;
static constexpr size_t OFF_S1  = OFF_W2T + SZ_W1T;
static constexpr size_t OFF_C1  = OFF_S1 + 8*1024*4;
static constexpr size_t OFF_U   = OFF_C1 + 8*1024*4;

extern "C" void kernel_launch(void* const* d_in, const int* in_sizes, int n_in,
                              void* d_out, int out_size, void* d_ws, size_t ws_size,
                              hipStream_t stream) {
  (void)in_sizes; (void)n_in; (void)out_size;
  const float* features = (const float*)d_in[0];
  const float* coords   = (const float*)d_in[1];
  const float* t_norm   = (const float*)d_in[2];
  const float* freqm    = (const float*)d_in[3];
  const float* omega    = (const float*)d_in[4];
  const float* in_w     = (const float*)d_in[5];
  const float* in_b     = (const float*)d_in[6];
  const float* ln1_g    = (const float*)d_in[7];
  const float* ln1_b    = (const float*)d_in[8];
  const float* slice_w  = (const float*)d_in[9];
  const float* slice_b  = (const float*)d_in[10];
  const float* qkv_w    = (const float*)d_in[11];
  const float* qkv_b    = (const float*)d_in[12];
  const float* aow      = (const float*)d_in[13];
  const float* aob      = (const float*)d_in[14];
  const float* ln2_g    = (const float*)d_in[15];
  const float* ln2_b    = (const float*)d_in[16];
  const float* f1w      = (const float*)d_in[17];
  const float* f1b      = (const float*)d_in[18];
  const float* f2w      = (const float*)d_in[19];
  const float* f2b      = (const float*)d_in[20];
  const float* out_w    = (const float*)d_in[21];
  const float* out_b    = (const float*)d_in[22];

  char* ws = (char*)d_ws;
  float*     X   = (float*)(ws + OFF_X);
  float*     Wb  = (float*)(ws + OFF_W);
  float*     ST  = (float*)(ws + OFF_ST);
  float*     S   = (float*)(ws + OFF_S);
  float*     WS  = (float*)(ws + OFF_WS);
  float*     O   = (float*)(ws + OFF_O);
  float*     SO  = (float*)(ws + OFF_SO);
  _Float16*  W1T = (_Float16*)(ws + OFF_W1T);
  _Float16*  W2T = (_Float16*)(ws + OFF_W2T);
  float*     S1  = (float*)(ws + OFF_S1);
  float*     C1  = (float*)(ws + OFF_C1);
  _Float16*  U   = (_Float16*)(ws + OFF_U);

  // chunk the u buffer if workspace is small (decision depends only on ws_size)
  int CH = 1;
  while (CH < 32 && OFF_U + (size_t)(BN/CH)*FF*2 > ws_size) CH <<= 1;
  int crows = BN / CH;

  k_prep_w1t<<<8192, 256, 0, stream>>>(f1w, ln2_g, W1T);
  k_prep_w2t<<<8192, 256, 0, stream>>>(f2w, W2T);
  k_prep_s1c1<<<dim3(4, 8), 256, 0, stream>>>(f1w, ln2_g, ln2_b, f1b, S1, C1);
  k_encode<<<1024, 256, 0, stream>>>(features, coords, t_norm, freqm, omega, in_w, in_b, X);

  for (int L = 0; L < NDEPTH; ++L){
    hipMemsetAsync(ws + OFF_S, 0, SZ_S + 1024, stream);
    k_slice<<<1024, 256, 0, stream>>>(X, Wb, S, WS,
        slice_w + (size_t)L*8192, slice_b + (size_t)L*32,
        ln1_g + (size_t)L*256, ln1_b + (size_t)L*256);
    k_mha<<<32, 256, 0, stream>>>(S, WS, O,
        qkv_w + (size_t)L*196608, qkv_b + (size_t)L*768);
    k_outproj<<<128, 256, 0, stream>>>(O, SO,
        aow + (size_t)L*65536, aob + (size_t)L*256);
    k_deslice<<<4096, 256, 0, stream>>>(X, Wb, SO, ST);
    for (int c = 0; c < CH; ++c){
      int c0 = c * crows;
      k_ffn1<<<dim3(8, crows/128), 256, 0, stream>>>(X,
          W1T + (size_t)L*262144, S1 + (size_t)L*1024, C1 + (size_t)L*1024, ST, U, c0);
      k_ffn2<<<dim3(2, crows/128), 256, 0, stream>>>(U,
          W2T + (size_t)L*262144, f2b + (size_t)L*256, X, c0);
    }
  }
  k_final<<<512, 256, 0, stream>>>(X, out_w, out_b, (float*)d_out);
}

// Round 6
// 7314.866 us; speedup vs baseline: 1.1115x; 1.1115x over previous
//
#include <hip/hip_runtime.h>

#define BB 4
#define NN 32768
#define BN 131072
#define WD 256
#define NDEPTH 8
#define MS 32
#define NH 8
#define DHD 32
#define FF 1024

typedef float f32x4 __attribute__((ext_vector_type(4)));
typedef float f32x2 __attribute__((ext_vector_type(2)));
typedef _Float16 f16x8 __attribute__((ext_vector_type(8)));
typedef _Float16 f16x4 __attribute__((ext_vector_type(4)));

__device__ __forceinline__ float rcp_(float x){ return __builtin_amdgcn_rcpf(x); }
__device__ __forceinline__ float rsq_(float x){ return __builtin_amdgcn_rsqf(x); }

// gelu (exact erf variant) via Abramowitz-Stegun 7.1.26, |err| <= 1.5e-7
__device__ __forceinline__ float gelu_f(float x){
  float z  = 0.70710678118654752f * x;
  float az = fabsf(z);
  float t  = rcp_(fmaf(0.3275911f, az, 1.0f));
  float p  = fmaf(t, 1.061405429f, -1.453152027f);
  p = fmaf(t, p, 1.421413741f);
  p = fmaf(t, p, -0.284496736f);
  p = fmaf(t, p, 0.254829592f);
  p = p * t;
  float e  = __expf(-az*az);
  float er = 1.0f - p*e;
  er = (z < 0.0f) ? -er : er;
  return 0.5f * x * (1.0f + er);
}

// ---------- prep: weight transpose/convert (once per call) ----------
__global__ __launch_bounds__(256) void k_prep_w1t(const float* __restrict__ f1w,
                                                  const float* __restrict__ ln2g,
                                                  _Float16* __restrict__ W1T){
  int id = blockIdx.x*256 + threadIdx.x;      // 8*1024*256
  int k = id & 255; int f = (id >> 8) & 1023; int i = id >> 18;
  W1T[id] = (_Float16)(ln2g[i*256+k] * f1w[(size_t)i*262144 + (size_t)k*1024 + f]);
}
__global__ __launch_bounds__(256) void k_prep_w2t(const float* __restrict__ f2w,
                                                  _Float16* __restrict__ W2T){
  int id = blockIdx.x*256 + threadIdx.x;      // 8*256*1024
  int k = id & 1023; int n = (id >> 10) & 255; int i = id >> 18;
  W2T[id] = (_Float16)(f2w[(size_t)i*262144 + (size_t)k*256 + n]);
}
__global__ __launch_bounds__(256) void k_prep_s1c1(const float* __restrict__ f1w,
                                                   const float* __restrict__ ln2g,
                                                   const float* __restrict__ ln2b,
                                                   const float* __restrict__ f1b,
                                                   float* __restrict__ S1, float* __restrict__ C1){
  int fb = blockIdx.x; int i = blockIdx.y; int t = threadIdx.x;
  int f = fb*256 + t;
  const float* w = f1w + (size_t)i*262144 + f;
  float s = 0.f, c = 0.f;
  for (int k = 0; k < 256; ++k){
    float wv = w[(size_t)k*1024];
    s = fmaf(ln2g[i*256+k], wv, s);
    c = fmaf(ln2b[i*256+k], wv, c);
  }
  S1[i*1024+f] = s;
  C1[i*1024+f] = c + f1b[i*1024+f];
}
// qkvwT[L][c][d] = qkv_w[L][d][c]  (768 x 256 per layer, f32)
__global__ __launch_bounds__(256) void k_prep_qkvt(const float* __restrict__ qkvw,
                                                   float* __restrict__ qkvwT){
  int id = blockIdx.x*256 + threadIdx.x;      // 8*768*256 = 1572864
  int d = id & 255; int cl = id >> 8;
  int c = cl % 768; int L = cl / 768;
  qkvwT[id] = qkvw[(size_t)L*196608 + (size_t)d*768 + c];
}

// ---------- encode: x = concat(features, LFF(coords), TE(t)) @ in_w + in_b ----------
__global__ __launch_bounds__(256) void k_encode(const float* __restrict__ feat,
                                                const float* __restrict__ coords,
                                                const float* __restrict__ tn,
                                                const float* __restrict__ fm,
                                                const float* __restrict__ om,
                                                const float* __restrict__ in_w,
                                                const float* __restrict__ in_b,
                                                float* __restrict__ X){
  __shared__ float inw[28*256];
  __shared__ float enc[8][28];
  int t = threadIdx.x;
  for (int i = 0; i < 28; ++i) inw[i*256+t] = in_w[i*256+t];
  float bv = in_b[t];
  int row0 = blockIdx.x * 128;
  __syncthreads();
  for (int it = 0; it < 16; ++it){
    int rbase = row0 + it*8;
    if (t < 224){
      int rr = t / 28, j = t - rr*28;
      int row = rbase + rr; int b = row >> 15;
      float v;
      if (j < 4){
        v = feat[(size_t)row*4 + j];
      } else if (j < 20){
        int fi = (j - 4) & 7;
        const float* cp = coords + (size_t)row*3;
        float pr = 6.2831853071795864f * (cp[0]*fm[fi] + cp[1]*fm[8+fi] + cp[2]*fm[16+fi]);
        v = (j < 12) ? sinf(pr) : cosf(pr);
      } else {
        int fi = (j - 20) & 3;
        float ang = om[fi] * (tn[b] * 1000.0f);
        v = (j < 24) ? sinf(ang) : cosf(ang);
      }
      enc[rr][j] = v;
    }
    __syncthreads();
    for (int rr = 0; rr < 8; ++rr){
      float a = bv;
      #pragma unroll 7
      for (int j = 0; j < 28; ++j) a = fmaf(enc[rr][j], inw[j*256+t], a);
      X[(size_t)(rbase+rr)*256 + t] = a;
    }
    __syncthreads();
  }
}

// ---------- K1: LN1 + slice logits + softmax -> w ; accumulate S & wsum ----------
// 4 rows per barrier set (was 1): 128 barriers/block instead of 512.
__global__ __launch_bounds__(256) void k_slice(const float* __restrict__ X,
                                               float* __restrict__ Wb,
                                               float* __restrict__ S,
                                               float* __restrict__ WS,
                                               const float* __restrict__ swp,
                                               const float* __restrict__ sbp,
                                               const float* __restrict__ g1p,
                                               const float* __restrict__ b1p){
  __shared__ float hl[4][256];
  __shared__ float part[4][256];
  __shared__ float wl[4][32];
  __shared__ float red[4][8];
  int t = threadIdx.x;
  int base = (t >> 5) << 5;
  int m = t & 31;
  float swreg[32];
  #pragma unroll
  for (int j = 0; j < 32; ++j) swreg[j] = swp[(size_t)(base+j)*32 + m];
  float g1 = g1p[t], b1 = b1p[t];
  float sbv = sbp[t & 31];
  float acc[32];
  #pragma unroll
  for (int i = 0; i < 32; ++i) acc[i] = 0.f;
  float wacc = 0.f;
  int row0 = blockIdx.x * 128;
  int b = row0 >> 15;
  int wv_id = t >> 6;
  for (int it = 0; it < 32; ++it){
    int rb = row0 + it*4;
    float xv[4], sm[4], qm[4];
    #pragma unroll
    for (int r = 0; r < 4; ++r) xv[r] = X[(size_t)(rb+r)*256 + t];
    #pragma unroll
    for (int r = 0; r < 4; ++r){ sm[r] = xv[r]; qm[r] = xv[r]*xv[r]; }
    #pragma unroll
    for (int off = 32; off; off >>= 1){
      #pragma unroll
      for (int r = 0; r < 4; ++r){ sm[r] += __shfl_xor(sm[r], off); qm[r] += __shfl_xor(qm[r], off); }
    }
    if ((t & 63) == 0){
      #pragma unroll
      for (int r = 0; r < 4; ++r){ red[r][wv_id*2] = sm[r]; red[r][wv_id*2+1] = qm[r]; }
    }
    __syncthreads();                                    // A
    float h[4];
    #pragma unroll
    for (int r = 0; r < 4; ++r){
      float sum = red[r][0]+red[r][2]+red[r][4]+red[r][6];
      float sq  = red[r][1]+red[r][3]+red[r][5]+red[r][7];
      float mu  = sum * (1.f/256.f);
      float var = sq * (1.f/256.f) - mu*mu;
      float rstd = rsq_(var + 1e-5f);
      h[r] = (xv[r] - mu)*rstd*g1 + b1;
      hl[r][t] = h[r];
    }
    __syncthreads();                                    // B
    #pragma unroll
    for (int r = 0; r < 4; ++r){
      float p = 0.f;
      #pragma unroll
      for (int j = 0; j < 32; ++j) p = fmaf(hl[r][base+j], swreg[j], p);
      part[r][t] = p;
    }
    __syncthreads();                                    // C
    if (t < 128){
      int r = t >> 5, mm = t & 31;
      float lg = sbv;
      #pragma unroll
      for (int g = 0; g < 8; ++g) lg += part[r][g*32 + mm];
      float mx = lg;
      #pragma unroll
      for (int off = 16; off; off >>= 1) mx = fmaxf(mx, __shfl_xor(mx, off));
      float e = __expf(lg - mx);
      float se = e;
      #pragma unroll
      for (int off = 16; off; off >>= 1) se += __shfl_xor(se, off);
      float wv = e * rcp_(se);
      wl[r][mm] = wv;
      Wb[(size_t)(rb+r)*32 + mm] = wv;
      wacc += wv;
    }
    __syncthreads();                                    // D
    #pragma unroll
    for (int r = 0; r < 4; ++r)
      #pragma unroll
      for (int i = 0; i < 32; ++i) acc[i] = fmaf(wl[r][i], h[r], acc[i]);
  }
  #pragma unroll 8
  for (int i = 0; i < 32; ++i) atomicAdd(&S[(size_t)(b*32+i)*256 + t], acc[i]);
  // block-local wsum reduction, then one atomic per m
  if (t < 128) ((float*)hl)[t] = wacc;
  __syncthreads();
  if (t < 32){
    float* f = (float*)hl;
    atomicAdd(&WS[b*32 + t], f[t] + f[32+t] + f[64+t] + f[96+t]);
  }
}

// ---------- K2: tiny MHA on (B, 32, 256); one block per (batch, head) ----------
// qkvwT is (768, 256) per layer -> contiguous f32x4 dot-product reads.
__global__ __launch_bounds__(256) void k_mha(const float* __restrict__ S,
                                             const float* __restrict__ WS,
                                             float* __restrict__ O,
                                             const float* __restrict__ qkvwT,
                                             const float* __restrict__ qkvb){
  __shared__ float zl[32*256];
  __shared__ float qkl[3][32][33];
  __shared__ float att[32][33];
  __shared__ float wsl[32];
  int t = threadIdx.x;
  int b = blockIdx.x >> 3, h = blockIdx.x & 7;
  if (t < 32) wsl[t] = rcp_(fmaxf(WS[b*32+t], 1e-8f));
  __syncthreads();
  #pragma unroll
  for (int i = 0; i < 8; ++i){
    int idx = i*1024 + t*4;
    int mm = idx >> 8; int d = idx & 255;
    f32x4 v = *reinterpret_cast<const f32x4*>(S + (size_t)(b*32+mm)*256 + d);
    v *= wsl[mm];
    *reinterpret_cast<f32x4*>(&zl[idx]) = v;
  }
  __syncthreads();
  for (int i = 0; i < 12; ++i){
    int o = i*256 + t;
    int which = o >> 10, rem = o & 1023, mm = rem >> 5, dh = rem & 31;
    int col = which*256 + h*32 + dh;
    const f32x4* zp = reinterpret_cast<const f32x4*>(&zl[mm*256]);
    const f32x4* wp = reinterpret_cast<const f32x4*>(qkvwT + (size_t)col*256);
    f32x4 av = {0.f,0.f,0.f,0.f};
    #pragma unroll 8
    for (int d4 = 0; d4 < 64; ++d4) av += zp[d4]*wp[d4];
    qkl[which][mm][dh] = av[0]+av[1]+av[2]+av[3] + qkvb[col];
  }
  __syncthreads();
  for (int i = 0; i < 4; ++i){
    int e = i*256 + t; int mm = e >> 5; int k2 = e & 31;
    float a = 0.f;
    #pragma unroll 8
    for (int d = 0; d < 32; ++d) a = fmaf(qkl[0][mm][d], qkl[1][k2][d], a);
    att[mm][k2] = a * 0.17677669529663687f;
  }
  __syncthreads();
  {
    int mm = t >> 3, j = t & 7;
    float v0 = att[mm][j], v1 = att[mm][j+8], v2 = att[mm][j+16], v3 = att[mm][j+24];
    float mx = fmaxf(fmaxf(v0, v1), fmaxf(v2, v3));
    #pragma unroll
    for (int off = 4; off; off >>= 1) mx = fmaxf(mx, __shfl_xor(mx, off));
    v0 = __expf(v0-mx); v1 = __expf(v1-mx); v2 = __expf(v2-mx); v3 = __expf(v3-mx);
    float sm = v0+v1+v2+v3;
    #pragma unroll
    for (int off = 4; off; off >>= 1) sm += __shfl_xor(sm, off);
    float inv = rcp_(sm);
    att[mm][j] = v0*inv; att[mm][j+8] = v1*inv; att[mm][j+16] = v2*inv; att[mm][j+24] = v3*inv;
  }
  __syncthreads();
  for (int i = 0; i < 4; ++i){
    int e = i*256 + t; int mm = e >> 5; int dh = e & 31;
    float a = 0.f;
    #pragma unroll 8
    for (int k2 = 0; k2 < 32; ++k2) a = fmaf(att[mm][k2], qkl[2][k2][dh], a);
    O[(size_t)(b*32+mm)*256 + h*32 + dh] = a;
  }
}

// ---------- K3: slices_out = o @ attn_out_w + attn_out_b ----------
__global__ __launch_bounds__(256) void k_outproj(const float* __restrict__ O,
                                                 float* __restrict__ SO,
                                                 const float* __restrict__ aow,
                                                 const float* __restrict__ aob){
  __shared__ float orow[256];
  int t = threadIdx.x; int row = blockIdx.x;
  orow[t] = O[(size_t)row*256 + t];
  __syncthreads();
  float a = aob[t];
  #pragma unroll 4
  for (int d = 0; d < 256; ++d) a = fmaf(orow[d], aow[(size_t)d*256 + t], a);
  SO[(size_t)row*256 + t] = a;
}

// ---------- K4: x += w @ slices_out ; write LN2 stats (rstd, rstd*mu) ----------
// 4 rows per barrier set: 16 barriers/block instead of 64.
__global__ __launch_bounds__(256) void k_deslice(float* __restrict__ X,
                                                 const float* __restrict__ Wb,
                                                 const float* __restrict__ SO,
                                                 float* __restrict__ ST){
  __shared__ float wrow[4][32];
  __shared__ float red[4][8];
  int t = threadIdx.x;
  int row0 = blockIdx.x * 32;
  int b = row0 >> 15;
  int wv_id = t >> 6;
  float soc[32];
  #pragma unroll 8
  for (int i = 0; i < 32; ++i) soc[i] = SO[(size_t)(b*32+i)*256 + t];
  for (int it = 0; it < 8; ++it){
    int rb = row0 + it*4;
    if (t < 128) wrow[t>>5][t&31] = Wb[(size_t)(rb + (t>>5))*32 + (t&31)];
    __syncthreads();                                    // bar1
    float xn[4], sm[4], qm[4];
    #pragma unroll
    for (int r = 0; r < 4; ++r){
      float xv = X[(size_t)(rb+r)*256 + t];
      float dv = 0.f;
      #pragma unroll
      for (int i = 0; i < 32; ++i) dv = fmaf(wrow[r][i], soc[i], dv);
      xn[r] = xv + dv;
      X[(size_t)(rb+r)*256 + t] = xn[r];
      sm[r] = xn[r]; qm[r] = xn[r]*xn[r];
    }
    #pragma unroll
    for (int off = 32; off; off >>= 1){
      #pragma unroll
      for (int r = 0; r < 4; ++r){ sm[r] += __shfl_xor(sm[r], off); qm[r] += __shfl_xor(qm[r], off); }
    }
    if ((t & 63) == 0){
      #pragma unroll
      for (int r = 0; r < 4; ++r){ red[r][wv_id*2] = sm[r]; red[r][wv_id*2+1] = qm[r]; }
    }
    __syncthreads();                                    // bar2
    if (t < 4){
      int r = t;
      float sum = red[r][0]+red[r][2]+red[r][4]+red[r][6];
      float sq  = red[r][1]+red[r][3]+red[r][5]+red[r][7];
      float mu  = sum * (1.f/256.f);
      float var = sq * (1.f/256.f) - mu*mu;
      float rstd = rsq_(var + 1e-5f);
      ST[(size_t)(rb+r)*2]   = rstd;
      ST[(size_t)(rb+r)*2+1] = rstd*mu;
    }
  }
}

// ---------- G1: u = gelu( rstd*(x@W1g) - (rstd*mu)*S1 + C1 ) , f16 out ----------
__global__ __launch_bounds__(256) void k_ffn1(const float* __restrict__ X,
                                              const _Float16* __restrict__ W1T,
                                              const float* __restrict__ S1,
                                              const float* __restrict__ C1,
                                              const float* __restrict__ ST,
                                              _Float16* __restrict__ U, int c0){
  __shared__ _Float16 As[128*40];
  __shared__ _Float16 Bs[128*40];
  __shared__ f32x2 stl[128];
  int t = threadIdx.x;
  int nb = blockIdx.x;
  int my = blockIdx.y;
  int row0 = c0 + my*128;
  int w = t >> 6, l = t & 63;
  int wm = w >> 1, wn = w & 1, lr = l & 15, lk = l >> 4;
  f32x4 acc[4][4] = {};
  for (int ks = 0; ks < 8; ++ks){
    int k0 = ks*32;
    {
      int r = t >> 3, qd = t & 7;
      #pragma unroll
      for (int i = 0; i < 4; ++i){
        int rr = i*32 + r;
        f32x4 v = *reinterpret_cast<const f32x4*>(X + (size_t)(row0+rr)*256 + k0 + qd*4);
        f16x4 hv; hv[0]=(_Float16)v[0]; hv[1]=(_Float16)v[1]; hv[2]=(_Float16)v[2]; hv[3]=(_Float16)v[3];
        *reinterpret_cast<f16x4*>(&As[rr*40 + qd*4]) = hv;
      }
      #pragma unroll
      for (int i = 0; i < 2; ++i){
        int e = i*256 + t; int fr = e >> 2; int qb = e & 3;
        f16x8 hv = *reinterpret_cast<const f16x8*>(W1T + (size_t)(nb*128+fr)*256 + k0 + qb*8);
        *reinterpret_cast<f16x8*>(&Bs[fr*40 + qb*8]) = hv;
      }
    }
    __syncthreads();
    f16x8 a[4], bf[4];
    #pragma unroll
    for (int i = 0; i < 4; ++i) a[i]  = *reinterpret_cast<const f16x8*>(&As[(64*wm + 16*i + lr)*40 + lk*8]);
    #pragma unroll
    for (int i = 0; i < 4; ++i) bf[i] = *reinterpret_cast<const f16x8*>(&Bs[(64*wn + 16*i + lr)*40 + lk*8]);
    #pragma unroll
    for (int mt = 0; mt < 4; ++mt)
      #pragma unroll
      for (int nt = 0; nt < 4; ++nt)
        acc[mt][nt] = __builtin_amdgcn_mfma_f32_16x16x32_f16(a[mt], bf[nt], acc[mt][nt], 0, 0, 0);
    __syncthreads();
  }
  if (t < 128) stl[t] = *reinterpret_cast<const f32x2*>(ST + (size_t)(row0+t)*2);
  __syncthreads();
  #pragma unroll
  for (int nt = 0; nt < 4; ++nt){
    int f = nb*128 + 64*wn + 16*nt + lr;
    float s1 = S1[f], c1 = C1[f];
    #pragma unroll
    for (int mt = 0; mt < 4; ++mt){
      int lrow0 = 64*wm + 16*mt + lk*4;
      #pragma unroll
      for (int e = 0; e < 4; ++e){
        f32x2 st2 = stl[lrow0 + e];
        float u = st2[0]*acc[mt][nt][e] - st2[1]*s1 + c1;
        U[(size_t)(my*128 + lrow0 + e)*1024 + f] = (_Float16)gelu_f(u);
      }
    }
  }
}

// ---------- G2: x += u @ W2 + b2 ----------
__global__ __launch_bounds__(256) void k_ffn2(const _Float16* __restrict__ U,
                                              const _Float16* __restrict__ W2T,
                                              const float* __restrict__ f2b,
                                              float* __restrict__ X, int c0){
  __shared__ _Float16 As[128*40];
  __shared__ _Float16 Bs[128*40];
  int t = threadIdx.x;
  int nb = blockIdx.x;
  int my = blockIdx.y;
  int w = t >> 6, l = t & 63;
  int wm = w >> 1, wn = w & 1, lr = l & 15, lk = l >> 4;
  f32x4 acc[4][4] = {};
  for (int ks = 0; ks < 32; ++ks){
    int k0 = ks*32;
    #pragma unroll
    for (int i = 0; i < 2; ++i){
      int e = i*256 + t; int r = e >> 2; int qb = e & 3;
      f16x8 hv  = *reinterpret_cast<const f16x8*>(U   + (size_t)(my*128+r)*1024 + k0 + qb*8);
      *reinterpret_cast<f16x8*>(&As[r*40 + qb*8]) = hv;
      f16x8 hv2 = *reinterpret_cast<const f16x8*>(W2T + (size_t)(nb*128+r)*1024 + k0 + qb*8);
      *reinterpret_cast<f16x8*>(&Bs[r*40 + qb*8]) = hv2;
    }
    __syncthreads();
    f16x8 a[4], bf[4];
    #pragma unroll
    for (int i = 0; i < 4; ++i) a[i]  = *reinterpret_cast<const f16x8*>(&As[(64*wm + 16*i + lr)*40 + lk*8]);
    #pragma unroll
    for (int i = 0; i < 4; ++i) bf[i] = *reinterpret_cast<const f16x8*>(&Bs[(64*wn + 16*i + lr)*40 + lk*8]);
    #pragma unroll
    for (int mt = 0; mt < 4; ++mt)
      #pragma unroll
      for (int nt = 0; nt < 4; ++nt)
        acc[mt][nt] = __builtin_amdgcn_mfma_f32_16x16x32_f16(a[mt], bf[nt], acc[mt][nt], 0, 0, 0);
    __syncthreads();
  }
  #pragma unroll
  for (int nt = 0; nt < 4; ++nt){
    int c = nb*128 + 64*wn + 16*nt + lr;
    float bv = f2b[c];
    #pragma unroll
    for (int mt = 0; mt < 4; ++mt){
      int gr = c0 + my*128 + 64*wm + 16*mt + lk*4;
      #pragma unroll
      for (int e = 0; e < 4; ++e){
        size_t idx = (size_t)(gr+e)*256 + c;
        X[idx] = X[idx] + acc[mt][nt][e] + bv;
      }
    }
  }
}

// ---------- final: out = x @ out_w + out_b ----------
__global__ __launch_bounds__(256) void k_final(const float* __restrict__ X,
                                               const float* __restrict__ out_w,
                                               const float* __restrict__ out_b,
                                               float* __restrict__ out){
  int t = threadIdx.x; int w = t >> 6; int l = t & 63;
  f32x4 ow[4];
  #pragma unroll
  for (int j = 0; j < 4; ++j) ow[j] = *reinterpret_cast<const f32x4*>(out_w + (4*l+j)*4);
  f32x4 ob = *reinterpret_cast<const f32x4*>(out_b);
  int row0 = blockIdx.x * 256;
  for (int it = 0; it < 64; ++it){
    int row = row0 + it*4 + w;
    f32x4 xv = *reinterpret_cast<const f32x4*>(X + (size_t)row*256 + 4*l);
    f32x4 p = ow[0]*xv[0];
    p += ow[1]*xv[1]; p += ow[2]*xv[2]; p += ow[3]*xv[3];
    #pragma unroll
    for (int off = 32; off; off >>= 1){
      p[0] += __shfl_xor(p[0], off);
      p[1] += __shfl_xor(p[1], off);
      p[2] += __shfl_xor(p[2], off);
      p[3] += __shfl_xor(p[3], off);
    }
    if (l == 0) *reinterpret_cast<f32x4*>(out + (size_t)row*4) = p + ob;
  }
}

// ---------- host ----------
static constexpr size_t OFF_X   = 0;
static constexpr size_t SZ_X    = (size_t)BN*256*4;            // 134217728
static constexpr size_t OFF_W   = OFF_X + SZ_X;
static constexpr size_t SZ_W    = (size_t)BN*32*4;             // 16777216
static constexpr size_t OFF_ST  = OFF_W + SZ_W;
static constexpr size_t SZ_ST   = (size_t)BN*2*4;              // 1048576
static constexpr size_t OFF_S   = OFF_ST + SZ_ST;
static constexpr size_t SZ_S    = (size_t)4*32*256*4;          // 131072
static constexpr size_t OFF_WS  = OFF_S + SZ_S;
static constexpr size_t OFF_O   = OFF_WS + 1024;
static constexpr size_t OFF_SO  = OFF_O + 131072;
static constexpr size_t OFF_W1T = OFF_SO + 131072;
static constexpr size_t SZ_W1T  = (size_t)8*1024*256*2;        // 4194304
static constexpr size_t OFF_W2T = OFF_W1T + SZ_W1T;
static constexpr size_t OFF_S1  = OFF_W2T + SZ_W1T;
static constexpr size_t OFF_C1  = OFF_S1 + 8*1024*4;
static constexpr size_t OFF_QT  = OFF_C1 + 8*1024*4;
static constexpr size_t SZ_QT   = (size_t)8*768*256*4;         // 6291456
static constexpr size_t OFF_U   = OFF_QT + SZ_QT;

extern "C" void kernel_launch(void* const* d_in, const int* in_sizes, int n_in,
                              void* d_out, int out_size, void* d_ws, size_t ws_size,
                              hipStream_t stream) {
  (void)in_sizes; (void)n_in; (void)out_size;
  const float* features = (const float*)d_in[0];
  const float* coords   = (const float*)d_in[1];
  const float* t_norm   = (const float*)d_in[2];
  const float* freqm    = (const float*)d_in[3];
  const float* omega    = (const float*)d_in[4];
  const float* in_w     = (const float*)d_in[5];
  const float* in_b     = (const float*)d_in[6];
  const float* ln1_g    = (const float*)d_in[7];
  const float* ln1_b    = (const float*)d_in[8];
  const float* slice_w  = (const float*)d_in[9];
  const float* slice_b  = (const float*)d_in[10];
  const float* qkv_w    = (const float*)d_in[11];
  const float* qkv_b    = (const float*)d_in[12];
  const float* aow      = (const float*)d_in[13];
  const float* aob      = (const float*)d_in[14];
  const float* ln2_g    = (const float*)d_in[15];
  const float* ln2_b    = (const float*)d_in[16];
  const float* f1w      = (const float*)d_in[17];
  const float* f1b      = (const float*)d_in[18];
  const float* f2w      = (const float*)d_in[19];
  const float* f2b      = (const float*)d_in[20];
  const float* out_w    = (const float*)d_in[21];
  const float* out_b    = (const float*)d_in[22];

  char* ws = (char*)d_ws;
  float*     X    = (float*)(ws + OFF_X);
  float*     Wb   = (float*)(ws + OFF_W);
  float*     ST   = (float*)(ws + OFF_ST);
  float*     S    = (float*)(ws + OFF_S);
  float*     WS   = (float*)(ws + OFF_WS);
  float*     O    = (float*)(ws + OFF_O);
  float*     SO   = (float*)(ws + OFF_SO);
  _Float16*  W1T  = (_Float16*)(ws + OFF_W1T);
  _Float16*  W2T  = (_Float16*)(ws + OFF_W2T);
  float*     S1   = (float*)(ws + OFF_S1);
  float*     C1   = (float*)(ws + OFF_C1);
  float*     QT   = (float*)(ws + OFF_QT);
  _Float16*  U    = (_Float16*)(ws + OFF_U);

  // chunk the u buffer if workspace is small (decision depends only on ws_size)
  int CH = 1;
  while (CH < 32 && OFF_U + (size_t)(BN/CH)*FF*2 > ws_size) CH <<= 1;
  int crows = BN / CH;

  k_prep_w1t<<<8192, 256, 0, stream>>>(f1w, ln2_g, W1T);
  k_prep_w2t<<<8192, 256, 0, stream>>>(f2w, W2T);
  k_prep_s1c1<<<dim3(4, 8), 256, 0, stream>>>(f1w, ln2_g, ln2_b, f1b, S1, C1);
  k_prep_qkvt<<<6144, 256, 0, stream>>>(qkv_w, QT);
  k_encode<<<1024, 256, 0, stream>>>(features, coords, t_norm, freqm, omega, in_w, in_b, X);

  for (int L = 0; L < NDEPTH; ++L){
    hipMemsetAsync(ws + OFF_S, 0, SZ_S + 1024, stream);
    k_slice<<<1024, 256, 0, stream>>>(X, Wb, S, WS,
        slice_w + (size_t)L*8192, slice_b + (size_t)L*32,
        ln1_g + (size_t)L*256, ln1_b + (size_t)L*256);
    k_mha<<<32, 256, 0, stream>>>(S, WS, O,
        QT + (size_t)L*196608, qkv_b + (size_t)L*768);
    k_outproj<<<128, 256, 0, stream>>>(O, SO,
        aow + (size_t)L*65536, aob + (size_t)L*256);
    k_deslice<<<4096, 256, 0, stream>>>(X, Wb, SO, ST);
    for (int c = 0; c < CH; ++c){
      int c0 = c * crows;
      k_ffn1<<<dim3(8, crows/128), 256, 0, stream>>>(X,
          W1T + (size_t)L*262144, S1 + (size_t)L*1024, C1 + (size_t)L*1024, ST, U, c0);
      k_ffn2<<<dim3(2, crows/128), 256, 0, stream>>>(U,
          W2T + (size_t)L*262144, f2b + (size_t)L*256, X, c0);
    }
  }
  k_final<<<512, 256, 0, stream>>>(X, out_w, out_b, (float*)d_out);
}